// Round 10
// baseline (87.055 us; speedup 1.0000x reference)
//
#include <hip/hip_runtime.h>
#include <math.h>

#define C 32
#define OUT_DIM 288
#define MAXDEG 64
#define AGG_ROWS 17
#define AGG_S (AGG_ROWS * 32)   // 544 floats per node, node-major
// agg rows: 0:a0a 1:a0b 2-4:a1a 5-7:a1b 8-12:a2 13:x0 14-16:x1

__device__ __forceinline__ float gelu_tanh(float x) {
    // jax.nn.gelu approximate=True
    float x3 = x * x * x;
    float t = tanhf(0.7978845608028654f * (x + 0.044715f * x3));
    return 0.5f * x * (1.0f + t);
}

__global__ void zero_kernel(int* __restrict__ p, int n) {
    int i = blockIdx.x * 256 + threadIdx.x;
    if (i < n) p[i] = 0;
}

// Scatter into fixed-stride bins + spherical-harmonic precompute.
// adj[r*MAXDEG + p] = {shx, shy, shz, sender_bits}; counts[r] ends as degree.
__global__ void scatter_sh_kernel(const int* __restrict__ recv,
                                  const int* __restrict__ senders,
                                  const float* __restrict__ pos, int E,
                                  int* __restrict__ counts, float4* __restrict__ adj) {
    int e = blockIdx.x * 256 + threadIdx.x;
    if (e < E) {
        const int r = recv[e];
        const int s = senders[e];
        const float rx = pos[r * 3 + 0] - pos[s * 3 + 0];
        const float ry = pos[r * 3 + 1] - pos[s * 3 + 1];
        const float rz = pos[r * 3 + 2] - pos[s * 3 + 2];
        const float nrm = sqrtf(rx * rx + ry * ry + rz * rz);
        const float f = 1.7320508075688772f / fmaxf(nrm, 1e-9f);  // sqrt(3)/|r|
        const int p = atomicAdd(&counts[r], 1);
        if (p < MAXDEG)
            adj[(size_t)r * MAXDEG + p] = make_float4(rx * f, ry * f, rz * f, __int_as_float(s));
    }
}

// K1: 1 wave per node, no LDS. Halves process interleaved edges with a 2-edge
// unroll -> 4 gather chains in flight. All 17 input rows written node-major.
__global__ __launch_bounds__(256) void edge_agg_kernel(
    const float* __restrict__ node0, const float* __restrict__ node1,
    const int* __restrict__ counts, const float4* __restrict__ adj,
    float* __restrict__ agg, int N)
{
    const int tid  = threadIdx.x;
    const int wv   = tid >> 6;
    const int lane = tid & 63;
    const int half = lane >> 5;
    const int c    = lane & 31;
    const int node = blockIdx.x * 4 + wv;
    const bool valid = (node < N);

    const float S2 = 0.70710678118654752f;   // 1/sqrt(2)
    const float S6 = 0.40824829046386302f;   // 1/sqrt(6)
    const float INV_SQRT3 = 0.57735026918962576f;
    const float INV_DEN = 1.0f / 16.0f;

    float ax0 = 0.f, atp0 = 0.f;
    float ax1x = 0.f, ax1y = 0.f, ax1z = 0.f;
    float at1x = 0.f, at1y = 0.f, at1z = 0.f;
    float a2v0 = 0.f, a2v1 = 0.f, a2v2 = 0.f, a2v3 = 0.f, a2v4 = 0.f;

#define EDGE_ACC(A, X0, U1)                                                 \
    {                                                                       \
        const float shx = (A).x, shy = (A).y, shz = (A).z;                  \
        ax0 += (X0);                                                        \
        atp0 += (U1).x * shx + (U1).y * shy + (U1).z * shz;                 \
        ax1x += (U1).x; ax1y += (U1).y; ax1z += (U1).z;                     \
        at1x += (X0) * shx; at1y += (X0) * shy; at1z += (X0) * shz;         \
        a2v0 += S2 * ((U1).x * shy + (U1).y * shx);                         \
        a2v1 += S2 * ((U1).y * shz + (U1).z * shy);                         \
        a2v2 += S6 * (2.f * (U1).z * shz - (U1).x * shx - (U1).y * shy);    \
        a2v3 += S2 * ((U1).x * shz + (U1).z * shx);                         \
        a2v4 += S2 * ((U1).x * shx - (U1).y * shy);                         \
    }

    if (valid) {
        const int deg = min(counts[node], MAXDEG);
        const int beg = node * MAXDEG;
        const int end = beg + deg;
        int k = beg + half;   // this half's edges: k, k+2, ...
        while (k + 2 < end) {
            const float4 A0 = adj[k];
            const float4 A1 = adj[k + 2];
            const int b0 = __float_as_int(A0.w) * C + c;
            const int b1 = __float_as_int(A1.w) * C + c;
            const float q0 = node0[b0];
            const float q1 = node0[b1];
            const float3 u0 = *(const float3*)(node1 + b0 * 3);
            const float3 u1 = *(const float3*)(node1 + b1 * 3);
            EDGE_ACC(A0, q0, u0);
            EDGE_ACC(A1, q1, u1);
            k += 4;
        }
        if (k < end) {
            const float4 A0 = adj[k];
            const int b0 = __float_as_int(A0.w) * C + c;
            const float q0 = node0[b0];
            const float3 u0 = *(const float3*)(node1 + b0 * 3);
            EDGE_ACC(A0, q0, u0);
        }
    }
#undef EDGE_ACC

    // combine halves (totals land in both halves)
    ax0  += __shfl_xor(ax0, 32, 64);
    atp0 += __shfl_xor(atp0, 32, 64);
    ax1x += __shfl_xor(ax1x, 32, 64);
    ax1y += __shfl_xor(ax1y, 32, 64);
    ax1z += __shfl_xor(ax1z, 32, 64);
    at1x += __shfl_xor(at1x, 32, 64);
    at1y += __shfl_xor(at1y, 32, 64);
    at1z += __shfl_xor(at1z, 32, 64);
    a2v0 += __shfl_xor(a2v0, 32, 64);
    a2v1 += __shfl_xor(a2v1, 32, 64);
    a2v2 += __shfl_xor(a2v2, 32, 64);
    a2v3 += __shfl_xor(a2v3, 32, 64);
    a2v4 += __shfl_xor(a2v4, 32, 64);

    if (valid) {
        float x0n = node0[node * C + c];
        const float3 xu = *(const float3*)(node1 + (node * C + c) * 3);

        float* ag = agg + (size_t)node * AGG_S + c;
        if (half == 0) {
            ag[0 * 32]  = ax0 * INV_DEN;
            ag[1 * 32]  = atp0 * (INV_DEN * INV_SQRT3);
            ag[2 * 32]  = ax1x * INV_DEN;
            ag[3 * 32]  = ax1y * INV_DEN;
            ag[4 * 32]  = ax1z * INV_DEN;
            ag[5 * 32]  = at1x * INV_DEN;
            ag[6 * 32]  = at1y * INV_DEN;
            ag[13 * 32] = x0n;
            ag[14 * 32] = xu.x;
        } else {
            ag[7 * 32]  = at1z * INV_DEN;
            ag[8 * 32]  = a2v0 * INV_DEN;
            ag[9 * 32]  = a2v1 * INV_DEN;
            ag[10 * 32] = a2v2 * INV_DEN;
            ag[11 * 32] = a2v3 * INV_DEN;
            ag[12 * 32] = a2v4 * INV_DEN;
            ag[15 * 32] = xu.y;
            ag[16 * 32] = xu.z;
        }
    }
}

__device__ __forceinline__ void load32(float (&a)[32], const float* __restrict__ p) {
#pragma unroll
    for (int i = 0; i < 8; ++i) {
        const float4 v = ((const float4*)p)[i];
        a[4 * i + 0] = v.x; a[4 * i + 1] = v.y;
        a[4 * i + 2] = v.z; a[4 * i + 3] = v.w;
    }
}

// fully-unrolled h[d] += sum_c a[c]*W[c*32+d]; all indices compile-time ->
// a[] stays in VGPRs, W uniform -> scalar loads + SGPR-operand FMAs.
__device__ __forceinline__ void gemm32_full(float (&h)[32], const float (&a)[32],
                                            const float* __restrict__ W) {
#pragma unroll
    for (int c = 0; c < 32; ++c) {
        const float ac = a[c];
#pragma unroll
        for (int d = 0; d < 32; ++d)
            h[d] = fmaf(ac, W[c * 32 + d], h[d]);
    }
}

// K2a: pre-linear. One generic dual-GEMM body shared by all 9 tasks (I$-resident).
// t=0: h=gelu(a0a*W0lo + a0b*W0hi); t=1..3: h=a1a_i*W1lo + a1b_i*W1hi;
// t=4..8: h=a2_m*W2.  -> hbuf[n][t][32]
__global__ __launch_bounds__(256) void pre_gemm_kernel(
    const float* __restrict__ agg,
    const float* __restrict__ Wpre0, const float* __restrict__ Wpre1,
    const float* __restrict__ Wpre2,
    float* __restrict__ hbuf, int N, int ngroups)
{
    const int wave_raw = blockIdx.x * 4 + (threadIdx.x >> 6);
    const int g = __builtin_amdgcn_readfirstlane(wave_raw / 9);
    const int t = __builtin_amdgcn_readfirstlane(wave_raw % 9);
    if (g >= ngroups) return;

    const int lane = threadIdx.x & 63;
    const int n = g * 64 + lane;
    const bool valid = (n < N);
    const int nn = valid ? n : (N - 1);
    const float* __restrict__ agp = agg + (size_t)nn * AGG_S;

    const float *A1, *A2 = nullptr, *W1, *W2 = nullptr;
    if (t == 0)      { A1 = agp;                  W1 = Wpre0; A2 = agp + 32;            W2 = Wpre0 + 1024; }
    else if (t <= 3) { A1 = agp + (1 + t) * 32;   W1 = Wpre1; A2 = agp + (4 + t) * 32;  W2 = Wpre1 + 1024; }
    else             { A1 = agp + (4 + t) * 32;   W1 = Wpre2; }

    float h[32];
#pragma unroll
    for (int d = 0; d < 32; ++d) h[d] = 0.f;

    float a[32];
    load32(a, A1);
    gemm32_full(h, a, W1);
    if (t <= 3) {               // wave-uniform branch; shared second-GEMM body
        load32(a, A2);
        gemm32_full(h, a, W2);
    }
    if (t == 0) {
#pragma unroll
        for (int d = 0; d < 32; ++d) h[d] = gelu_tanh(h[d]);
    }

    if (valid) {
        float* hp = hbuf + ((size_t)n * 9 + t) * 32;
#pragma unroll
        for (int q = 0; q < 8; ++q)
            *(float4*)&hp[q * 4] = make_float4(h[q*4], h[q*4+1], h[q*4+2], h[q*4+3]);
    }
}

// K2b: post-linear + shortcut, same shared dual-GEMM body.
// t=0: o=h0*Wpost0 + x0*Wsc0 -> po[d]; t=1..3: o=h1i*Wpost1 + x1i*Wsc1 ->
// po[32+d*3+i]; t=4..8: o=h2m*Wpost2 -> po[128+d*5+m].
__global__ __launch_bounds__(256) void post_gemm_kernel(
    const float* __restrict__ agg, const float* __restrict__ hbuf,
    const float* __restrict__ Wpost0, const float* __restrict__ Wpost1,
    const float* __restrict__ Wpost2,
    const float* __restrict__ Wsc0, const float* __restrict__ Wsc1,
    float* __restrict__ out, int N, int ngroups)
{
    const int wave_raw = blockIdx.x * 4 + (threadIdx.x >> 6);
    const int g = __builtin_amdgcn_readfirstlane(wave_raw / 9);
    const int t = __builtin_amdgcn_readfirstlane(wave_raw % 9);
    if (g >= ngroups) return;

    const int lane = threadIdx.x & 63;
    const int n = g * 64 + lane;
    const bool valid = (n < N);
    const int nn = valid ? n : (N - 1);
    const float* __restrict__ agp = agg + (size_t)nn * AGG_S;
    const float* __restrict__ A1 = hbuf + ((size_t)nn * 9 + t) * 32;

    const float *A2 = nullptr, *W1, *W2 = nullptr;
    int base, stride;
    if (t == 0)      { W1 = Wpost0; A2 = agp + 13 * 32;        W2 = Wsc0; base = 0;            stride = 1; }
    else if (t <= 3) { W1 = Wpost1; A2 = agp + (13 + t) * 32;  W2 = Wsc1; base = 32 + (t - 1); stride = 3; }
    else             { W1 = Wpost2;                                        base = 128 + (t - 4); stride = 5; }

    float h[32];
#pragma unroll
    for (int d = 0; d < 32; ++d) h[d] = 0.f;

    float a[32];
    load32(a, A1);
    gemm32_full(h, a, W1);
    if (t <= 3) {
        load32(a, A2);
        gemm32_full(h, a, W2);
    }

    if (valid) {
        float* po = out + (size_t)n * OUT_DIM + base;
#pragma unroll
        for (int d = 0; d < 32; ++d) po[d * stride] = h[d];
    }
}

extern "C" void kernel_launch(void* const* d_in, const int* in_sizes, int n_in,
                              void* d_out, int out_size, void* d_ws, size_t ws_size,
                              hipStream_t stream) {
    const float* node0   = (const float*)d_in[0];
    const float* node1   = (const float*)d_in[1];
    const float* pos     = (const float*)d_in[2];
    const int*   senders = (const int*)d_in[3];
    const int*   recv    = (const int*)d_in[4];
    const float* Wpre0   = (const float*)d_in[5];
    const float* Wpre1   = (const float*)d_in[6];
    const float* Wpre2   = (const float*)d_in[7];
    const float* Wpost0  = (const float*)d_in[8];
    const float* Wpost1  = (const float*)d_in[9];
    const float* Wpost2  = (const float*)d_in[10];
    const float* Wsc0    = (const float*)d_in[11];
    const float* Wsc1    = (const float*)d_in[12];
    float* out = (float*)d_out;

    const int N = in_sizes[2] / 3;
    const int E = in_sizes[3];

    int* counts = (int*)d_ws;
    size_t adj_off = ((size_t)N * sizeof(int) + 15) & ~(size_t)15;
    float4* adj = (float4*)((char*)d_ws + adj_off);
    float* agg  = (float*)((char*)d_ws + adj_off + (size_t)N * MAXDEG * sizeof(float4));
    float* hbuf = agg + (size_t)N * AGG_S;

    zero_kernel<<<(N + 255) / 256, 256, 0, stream>>>(counts, N);
    scatter_sh_kernel<<<(E + 255) / 256, 256, 0, stream>>>(recv, senders, pos, E, counts, adj);
    edge_agg_kernel<<<(N + 3) / 4, 256, 0, stream>>>(node0, node1, counts, adj, agg, N);

    const int ngroups = (N + 63) / 64;
    const int nwaves = ngroups * 9;
    pre_gemm_kernel<<<(nwaves + 3) / 4, 256, 0, stream>>>(
        agg, Wpre0, Wpre1, Wpre2, hbuf, N, ngroups);
    post_gemm_kernel<<<(nwaves + 3) / 4, 256, 0, stream>>>(
        agg, hbuf, Wpost0, Wpost1, Wpost2, Wsc0, Wsc1, out, N, ngroups);
}

// Round 11
// 51.922 us; speedup vs baseline: 1.6767x; 1.6767x over previous
//
#include <hip/hip_runtime.h>
#include <math.h>

#define C 32
#define OUT_DIM 288
#define MAXDEG 64
#define AGG_ROWS 17
#define AGG_S (AGG_ROWS * 32)   // 544 ushorts per node, node-major (bf16)
// agg rows: 0:a0a 1:a0b 2-4:a1a 5-7:a1b 8-12:a2 13:x0 14-16:x1

typedef __attribute__((ext_vector_type(8))) short short8v;   // 8 bf16 (4 VGPRs)
typedef __attribute__((ext_vector_type(4))) float float4v;   // MFMA accumulator

__device__ __forceinline__ float4v mfma_bf16(short8v a, short8v b, float4v c) {
    return __builtin_amdgcn_mfma_f32_16x16x32_bf16(a, b, c, 0, 0, 0);
}

// f32 -> bf16 bits, round-to-nearest-even
__device__ __forceinline__ unsigned short f2b(float x) {
    unsigned int u = __float_as_uint(x);
    u = u + 0x7FFFu + ((u >> 16) & 1u);
    return (unsigned short)(u >> 16);
}

__device__ __forceinline__ float gelu_tanh(float x) {
    // jax.nn.gelu approximate=True
    float x3 = x * x * x;
    float t = tanhf(0.7978845608028654f * (x + 0.044715f * x3));
    return 0.5f * x * (1.0f + t);
}

__global__ void zero_kernel(int* __restrict__ p, int n) {
    int i = blockIdx.x * 256 + threadIdx.x;
    if (i < n) p[i] = 0;
}

// Scatter into fixed-stride bins + spherical-harmonic precompute.
__global__ void scatter_sh_kernel(const int* __restrict__ recv,
                                  const int* __restrict__ senders,
                                  const float* __restrict__ pos, int E,
                                  int* __restrict__ counts, float4* __restrict__ adj) {
    int e = blockIdx.x * 256 + threadIdx.x;
    if (e < E) {
        const int r = recv[e];
        const int s = senders[e];
        const float rx = pos[r * 3 + 0] - pos[s * 3 + 0];
        const float ry = pos[r * 3 + 1] - pos[s * 3 + 1];
        const float rz = pos[r * 3 + 2] - pos[s * 3 + 2];
        const float nrm = sqrtf(rx * rx + ry * ry + rz * rz);
        const float f = 1.7320508075688772f / fmaxf(nrm, 1e-9f);  // sqrt(3)/|r|
        const int p = atomicAdd(&counts[r], 1);
        if (p < MAXDEG)
            adj[(size_t)r * MAXDEG + p] = make_float4(rx * f, ry * f, rz * f, __int_as_float(s));
    }
}

// K1: 1 wave per node; halves interleave edges with 2-edge unroll (4 chains).
// All 17 rows written node-major as bf16.
__global__ __launch_bounds__(256) void edge_agg_kernel(
    const float* __restrict__ node0, const float* __restrict__ node1,
    const int* __restrict__ counts, const float4* __restrict__ adj,
    unsigned short* __restrict__ aggb, int N)
{
    const int tid  = threadIdx.x;
    const int wv   = tid >> 6;
    const int lane = tid & 63;
    const int half = lane >> 5;
    const int c    = lane & 31;
    const int node = blockIdx.x * 4 + wv;
    const bool valid = (node < N);

    const float S2 = 0.70710678118654752f;   // 1/sqrt(2)
    const float S6 = 0.40824829046386302f;   // 1/sqrt(6)
    const float INV_SQRT3 = 0.57735026918962576f;
    const float INV_DEN = 1.0f / 16.0f;

    float ax0 = 0.f, atp0 = 0.f;
    float ax1x = 0.f, ax1y = 0.f, ax1z = 0.f;
    float at1x = 0.f, at1y = 0.f, at1z = 0.f;
    float a2v0 = 0.f, a2v1 = 0.f, a2v2 = 0.f, a2v3 = 0.f, a2v4 = 0.f;

#define EDGE_ACC(A, X0, U1)                                                 \
    {                                                                       \
        const float shx = (A).x, shy = (A).y, shz = (A).z;                  \
        ax0 += (X0);                                                        \
        atp0 += (U1).x * shx + (U1).y * shy + (U1).z * shz;                 \
        ax1x += (U1).x; ax1y += (U1).y; ax1z += (U1).z;                     \
        at1x += (X0) * shx; at1y += (X0) * shy; at1z += (X0) * shz;         \
        a2v0 += S2 * ((U1).x * shy + (U1).y * shx);                         \
        a2v1 += S2 * ((U1).y * shz + (U1).z * shy);                         \
        a2v2 += S6 * (2.f * (U1).z * shz - (U1).x * shx - (U1).y * shy);    \
        a2v3 += S2 * ((U1).x * shz + (U1).z * shx);                         \
        a2v4 += S2 * ((U1).x * shx - (U1).y * shy);                         \
    }

    if (valid) {
        const int deg = min(counts[node], MAXDEG);
        const int beg = node * MAXDEG;
        const int end = beg + deg;
        int k = beg + half;
        while (k + 2 < end) {
            const float4 A0 = adj[k];
            const float4 A1 = adj[k + 2];
            const int b0 = __float_as_int(A0.w) * C + c;
            const int b1 = __float_as_int(A1.w) * C + c;
            const float q0 = node0[b0];
            const float q1 = node0[b1];
            const float3 u0 = *(const float3*)(node1 + b0 * 3);
            const float3 u1 = *(const float3*)(node1 + b1 * 3);
            EDGE_ACC(A0, q0, u0);
            EDGE_ACC(A1, q1, u1);
            k += 4;
        }
        if (k < end) {
            const float4 A0 = adj[k];
            const int b0 = __float_as_int(A0.w) * C + c;
            const float q0 = node0[b0];
            const float3 u0 = *(const float3*)(node1 + b0 * 3);
            EDGE_ACC(A0, q0, u0);
        }
    }
#undef EDGE_ACC

    ax0  += __shfl_xor(ax0, 32, 64);
    atp0 += __shfl_xor(atp0, 32, 64);
    ax1x += __shfl_xor(ax1x, 32, 64);
    ax1y += __shfl_xor(ax1y, 32, 64);
    ax1z += __shfl_xor(ax1z, 32, 64);
    at1x += __shfl_xor(at1x, 32, 64);
    at1y += __shfl_xor(at1y, 32, 64);
    at1z += __shfl_xor(at1z, 32, 64);
    a2v0 += __shfl_xor(a2v0, 32, 64);
    a2v1 += __shfl_xor(a2v1, 32, 64);
    a2v2 += __shfl_xor(a2v2, 32, 64);
    a2v3 += __shfl_xor(a2v3, 32, 64);
    a2v4 += __shfl_xor(a2v4, 32, 64);

    if (valid) {
        float x0n = node0[node * C + c];
        const float3 xu = *(const float3*)(node1 + (node * C + c) * 3);

        unsigned short* ag = aggb + (size_t)node * AGG_S + c;
        if (half == 0) {
            ag[0 * 32]  = f2b(ax0 * INV_DEN);
            ag[1 * 32]  = f2b(atp0 * (INV_DEN * INV_SQRT3));
            ag[2 * 32]  = f2b(ax1x * INV_DEN);
            ag[3 * 32]  = f2b(ax1y * INV_DEN);
            ag[4 * 32]  = f2b(ax1z * INV_DEN);
            ag[5 * 32]  = f2b(at1x * INV_DEN);
            ag[6 * 32]  = f2b(at1y * INV_DEN);
            ag[13 * 32] = f2b(x0n);
            ag[14 * 32] = f2b(xu.x);
        } else {
            ag[7 * 32]  = f2b(at1z * INV_DEN);
            ag[8 * 32]  = f2b(a2v0 * INV_DEN);
            ag[9 * 32]  = f2b(a2v1 * INV_DEN);
            ag[10 * 32] = f2b(a2v2 * INV_DEN);
            ag[11 * 32] = f2b(a2v3 * INV_DEN);
            ag[12 * 32] = f2b(a2v4 * INV_DEN);
            ag[15 * 32] = f2b(xu.y);
            ag[16 * 32] = f2b(xu.z);
        }
    }
}

// K2: fused node update via MFMA. One wave = one (16-node tile, task t).
// pre-GEMM (K=32 or 64) -> [gelu] -> in-wave LDS transpose -> post-GEMM
// (+shortcut for t<=3) -> scattered f32 store.
// Layouts (16x16x32 bf16): A: row=lane&15, k=(lane>>4)*8+j; B: col=lane&15,
// k=(lane>>4)*8+j; C/D: col=lane&15, row=(lane>>4)*4+reg [HW-verified].
__global__ __launch_bounds__(256) void node_mfma_kernel(
    const unsigned short* __restrict__ aggb,
    const float* __restrict__ Wpre0, const float* __restrict__ Wpre1,
    const float* __restrict__ Wpre2,
    const float* __restrict__ Wpost0, const float* __restrict__ Wpost1,
    const float* __restrict__ Wpost2,
    const float* __restrict__ Wsc0, const float* __restrict__ Wsc1,
    float* __restrict__ out, int N, int ntiles)
{
    __shared__ unsigned short tr[4][16][48];   // per-wave transpose slab (stride 96B, 16B-aligned)

    const int wv   = threadIdx.x >> 6;
    const int wave = blockIdx.x * 4 + wv;
    const int tile = __builtin_amdgcn_readfirstlane(wave / 9);
    const int t    = __builtin_amdgcn_readfirstlane(wave % 9);
    if (tile >= ntiles) return;

    const int lane = threadIdx.x & 63;
    const int r    = lane & 15;
    const int kg   = lane >> 4;
    const int k0   = kg * 8;

    // task-dependent selections (wave-uniform)
    const float *Wp1, *Wp2 = nullptr, *Wq1, *Wq2 = nullptr;
    int rowA1, rowA2 = -1, rowX = -1, obase, ostride;
    if (t == 0) {
        rowA1 = 0; rowA2 = 1; rowX = 13;
        Wp1 = Wpre0; Wp2 = Wpre0 + 1024; Wq1 = Wpost0; Wq2 = Wsc0;
        obase = 0; ostride = 1;
    } else if (t <= 3) {
        const int i = t - 1;
        rowA1 = 2 + i; rowA2 = 5 + i; rowX = 14 + i;
        Wp1 = Wpre1; Wp2 = Wpre1 + 1024; Wq1 = Wpost1; Wq2 = Wsc1;
        obase = 32 + i; ostride = 3;
    } else {
        const int m = t - 4;
        rowA1 = 8 + m;
        Wp1 = Wpre2; Wq1 = Wpost2;
        obase = 128 + m; ostride = 5;
    }

    // ---- B fragments (built once per wave, reused across the tile) ----
    short8v bp1[2], bp2[2], bq1[2], bq2[2];
#pragma unroll
    for (int dt = 0; dt < 2; ++dt) {
        const int d = dt * 16 + r;
#pragma unroll
        for (int j = 0; j < 8; ++j) {
            bp1[dt][j] = (short)f2b(Wp1[(k0 + j) * 32 + d]);
            bq1[dt][j] = (short)f2b(Wq1[(k0 + j) * 32 + d]);
        }
    }
    if (rowA2 >= 0) {
#pragma unroll
        for (int dt = 0; dt < 2; ++dt) {
            const int d = dt * 16 + r;
#pragma unroll
            for (int j = 0; j < 8; ++j) {
                bp2[dt][j] = (short)f2b(Wp2[(k0 + j) * 32 + d]);
                bq2[dt][j] = (short)f2b(Wq2[(k0 + j) * 32 + d]);
            }
        }
    }

    const int node = tile * 16 + r;
    const int nclamp = node < N ? node : (N - 1);
    const unsigned short* ap = aggb + (size_t)nclamp * AGG_S;

    // ---- pre-GEMM ----
    float4v acc0 = {0.f, 0.f, 0.f, 0.f};
    float4v acc1 = {0.f, 0.f, 0.f, 0.f};
    {
        const short8v a1 = *(const short8v*)(ap + rowA1 * 32 + k0);
        acc0 = mfma_bf16(a1, bp1[0], acc0);
        acc1 = mfma_bf16(a1, bp1[1], acc1);
    }
    if (rowA2 >= 0) {
        const short8v a2 = *(const short8v*)(ap + rowA2 * 32 + k0);
        acc0 = mfma_bf16(a2, bp2[0], acc0);
        acc1 = mfma_bf16(a2, bp2[1], acc1);
    }
    if (t == 0) {
#pragma unroll
        for (int q = 0; q < 4; ++q) {
            acc0[q] = gelu_tanh(acc0[q]);
            acc1[q] = gelu_tanh(acc1[q]);
        }
    }

    // ---- in-wave transpose: C layout -> A layout ----
#pragma unroll
    for (int q = 0; q < 4; ++q) {
        tr[wv][kg * 4 + q][r]      = f2b(acc0[q]);
        tr[wv][kg * 4 + q][16 + r] = f2b(acc1[q]);
    }
    asm volatile("s_waitcnt lgkmcnt(0)" ::: "memory");
    __builtin_amdgcn_sched_barrier(0);

    // ---- post-GEMM ----
    const short8v ha = *(const short8v*)&tr[wv][r][k0];
    float4v o0 = {0.f, 0.f, 0.f, 0.f};
    float4v o1 = {0.f, 0.f, 0.f, 0.f};
    o0 = mfma_bf16(ha, bq1[0], o0);
    o1 = mfma_bf16(ha, bq1[1], o1);
    if (rowX >= 0) {
        const short8v xa = *(const short8v*)(ap + rowX * 32 + k0);
        o0 = mfma_bf16(xa, bq2[0], o0);
        o1 = mfma_bf16(xa, bq2[1], o1);
    }

    // ---- store (C layout: row = kg*4+q, col = r / 16+r) ----
#pragma unroll
    for (int q = 0; q < 4; ++q) {
        const int nodeo = tile * 16 + kg * 4 + q;
        if (nodeo < N) {
            float* po = out + (size_t)nodeo * OUT_DIM + obase;
            po[r * ostride]        = o0[q];
            po[(16 + r) * ostride] = o1[q];
        }
    }
}

extern "C" void kernel_launch(void* const* d_in, const int* in_sizes, int n_in,
                              void* d_out, int out_size, void* d_ws, size_t ws_size,
                              hipStream_t stream) {
    const float* node0   = (const float*)d_in[0];
    const float* node1   = (const float*)d_in[1];
    const float* pos     = (const float*)d_in[2];
    const int*   senders = (const int*)d_in[3];
    const int*   recv    = (const int*)d_in[4];
    const float* Wpre0   = (const float*)d_in[5];
    const float* Wpre1   = (const float*)d_in[6];
    const float* Wpre2   = (const float*)d_in[7];
    const float* Wpost0  = (const float*)d_in[8];
    const float* Wpost1  = (const float*)d_in[9];
    const float* Wpost2  = (const float*)d_in[10];
    const float* Wsc0    = (const float*)d_in[11];
    const float* Wsc1    = (const float*)d_in[12];
    float* out = (float*)d_out;

    const int N = in_sizes[2] / 3;
    const int E = in_sizes[3];

    int* counts = (int*)d_ws;
    size_t adj_off = ((size_t)N * sizeof(int) + 15) & ~(size_t)15;
    float4* adj = (float4*)((char*)d_ws + adj_off);
    unsigned short* aggb = (unsigned short*)((char*)d_ws + adj_off + (size_t)N * MAXDEG * sizeof(float4));

    zero_kernel<<<(N + 255) / 256, 256, 0, stream>>>(counts, N);
    scatter_sh_kernel<<<(E + 255) / 256, 256, 0, stream>>>(recv, senders, pos, E, counts, adj);
    edge_agg_kernel<<<(N + 3) / 4, 256, 0, stream>>>(node0, node1, counts, adj, aggb, N);

    const int ntiles = (N + 15) / 16;
    const int nwaves = ntiles * 9;
    node_mfma_kernel<<<(nwaves + 3) / 4, 256, 0, stream>>>(
        aggb,
        Wpre0, Wpre1, Wpre2, Wpost0, Wpost1, Wpost2, Wsc0, Wsc1,
        out, N, ntiles);
}